// Round 4
// baseline (1116.415 us; speedup 1.0000x reference)
//
#include <hip/hip_runtime.h>

// MSDNet on gfx950 — round 4: pair fusion + float4 taps + sane occupancy.
// ws layout: GUARD + 29 zero-halo-padded fp32 planes x 4 batches + GUARD.
//   subplane (c*NB + b), each HP x WP, interior at [HALO..HALO+511].
// Pair kernel <I>: phase A computes h_I on a D1-extended 64x16 tile -> LDS;
// phase B computes h_{I+1} on the interior from the same global planes + LDS.
// Every tap is an unaligned-float4 load (4 px/thread/strip): 16B per
// outstanding load -> 4x the latency-bound throughput of scalar taps.
// Dilation pairs are (odd,even) so EW = 64+2*D1 is a multiple of 4: strips
// tile the extended region exactly. Invalid (outside-image) extended pixels
// load garbage from guard/halo unconditionally and are zero-masked at the
// LDS write (= conv zero-padding semantics).

#define MSD_DEPTH 30
#define NB 4
#define IH 512
#define IW 512
#define HALO 12
#define WP (IW + 2 * HALO) /* 536 */
#define HP (IH + 2 * HALO) /* 536 */
#define PLANE ((size_t)WP * (size_t)HP)
#define CSTRIDE ((size_t)NB * PLANE)
#define NPIX (NB * IH * IW)
#define NPLANES 29               /* planes 0..28 stored; h28/h29 never written */
#define GUARD ((size_t)(32 * WP))

typedef float f4 __attribute__((ext_vector_type(4)));
typedef f4 f4u __attribute__((aligned(4)));

__device__ __forceinline__ f4 ld4(const float* p) { return *(const f4u*)p; }

// ---------------------------------------------------------------------------
__global__ __launch_bounds__(256) void zero_halo_kernel(float* __restrict__ ws) {
    const int per = WP * HP - IW * IH; // 25152
    long idx = (long)blockIdx.x * 256 + threadIdx.x;
    const long total = (long)per * NPLANES * NB;
    if (idx >= total) return;
    int sub = (int)(idx / per);
    int rem = (int)(idx % per);
    int r, c;
    if (rem < HALO * WP) {
        r = rem / WP; c = rem % WP;
    } else if (rem < 2 * HALO * WP) {
        int t = rem - HALO * WP;
        r = (IH + HALO) + t / WP; c = t % WP;
    } else {
        int t = rem - 2 * HALO * WP;
        r = HALO + t / (2 * HALO);
        int u = t % (2 * HALO);
        c = (u < HALO) ? u : (IW + u);
    }
    ws[GUARD + (size_t)sub * PLANE + (size_t)r * WP + c] = 0.0f;
}

// ---------------------------------------------------------------------------
__global__ __launch_bounds__(256) void scale_in_kernel(const float* __restrict__ x,
                                                       float* __restrict__ ws,
                                                       const float* __restrict__ sw,
                                                       const float* __restrict__ sb) {
    int s = blockIdx.x * 256 + threadIdx.x; // strip id, 4 px each
    int idx = s * 4;
    int w = idx & (IW - 1);
    int t = idx >> 9;
    int h = t & (IH - 1);
    int b = t >> 9;
    f4 v = ld4(x + idx) * sw[0] + sb[0];
    *(f4*)(ws + GUARD + (size_t)b * PLANE + (size_t)(h + HALO) * WP + (w + HALO)) = v;
}

// ---------------------------------------------------------------------------
template <int I>
__global__ __launch_bounds__(256) void pair_kernel(float* __restrict__ ws,
                                                   const float* __restrict__ Wmsd,
                                                   const float* __restrict__ bias,
                                                   const float* __restrict__ convW,
                                                   const float* __restrict__ convB,
                                                   const float* __restrict__ soutw,
                                                   const float* __restrict__ soutb,
                                                   float* __restrict__ out) {
    constexpr int D0 = (I % 10) + 1;
    constexpr int D1 = ((I + 1) % 10) + 1;     // even -> EW % 4 == 0
    constexpr int NC = I + 1;                  // input planes for depth I
    constexpr bool LAST = (I == MSD_DEPTH - 2);
    constexpr int TW = 64, TH = 16;
    constexpr int EW = TW + 2 * D1;            // ext tile width (mult of 4)
    constexpr int EH = TH + 2 * D1;
    constexpr int SR = EW / 4;                 // strips per ext row
    constexpr int TS = EH * SR;                // total ext strips
    constexpr int NS = (TS + 255) / 256;       // ext strips per thread (2..3)

    __shared__ float h_lds[EH * EW];

    const int tid = threadIdx.x;
    const int bid = blockIdx.x;
    // XCD band swizzle: xcd = bid&7; each XCD owns a contiguous 256-row band
    // of one image (16 tile-rows) so vertical halo rows stay in its 4MB L2.
    const int xcd = bid & 7;
    const int k = bid >> 3;                    // 0..127
    const int b = xcd >> 1;                    // 2 XCDs per image
    const int ty = (xcd & 1) * 16 + (k >> 3);  // 0..31 tile rows (16 px)
    const int tx = k & 7;                      // 0..7 tile cols (64 px)
    const int gx0 = tx * TW, gy0 = ty * TH;

    float* const P = ws + GUARD;
    const float* const wsb = P + (size_t)b * PLANE;
    const int safe_off = (gy0 + HALO) * WP + (gx0 + HALO);

    // Phase-A strip offsets (dead strips -> safe interior, skipped at write)
    int offA[NS];
    f4 acc0[NS];
#pragma unroll
    for (int kk = 0; kk < NS; ++kk) {
        acc0[kk] = (f4)0.f;
        int s = tid + kk * 256;
        int row = s / SR;
        int c4 = (s - row * SR) * 4;
        int gy = gy0 - D1 + row;
        int gx = gx0 - D1 + c4;
        offA[kk] = (s < TS) ? ((gy + HALO) * WP + gx + HALO) : safe_off;
    }

    // Phase-B strip (1 per thread): 64x16 interior = 256 strips
    const int iy = tid >> 4;
    const int ix4 = (tid & 15) * 4;
    const int offB = (gy0 + iy + HALO) * WP + (gx0 + ix4 + HALO);
    f4 acc1 = (f4)0.f;
    f4 ydot = (f4)0.f;

    // Single pass over input planes: accumulate both depths' contributions.
    const float* pb = wsb;
    const float* w0p = Wmsd + (size_t)I * (MSD_DEPTH * 9);
    const float* w1p = Wmsd + (size_t)(I + 1) * (MSD_DEPTH * 9);
    for (int c = 0; c < NC; ++c, pb += CSTRIDE) {
        const float* w0 = w0p + c * 9;
        const float* w1 = w1p + c * 9;
#pragma unroll
        for (int kk = 0; kk < NS; ++kk) {
            const float* p = pb + offA[kk];
            acc0[kk] += ld4(p - D0 * WP - D0) * w0[0] + ld4(p - D0 * WP) * w0[1] + ld4(p - D0 * WP + D0) * w0[2]
                      + ld4(p - D0)           * w0[3] + ld4(p)           * w0[4] + ld4(p + D0)           * w0[5]
                      + ld4(p + D0 * WP - D0) * w0[6] + ld4(p + D0 * WP) * w0[7] + ld4(p + D0 * WP + D0) * w0[8];
        }
        {
            const float* p = pb + offB;
            f4 ctr = ld4(p);
            acc1 += ld4(p - D1 * WP - D1) * w1[0] + ld4(p - D1 * WP) * w1[1] + ld4(p - D1 * WP + D1) * w1[2]
                  + ld4(p - D1)           * w1[3] + ctr               * w1[4] + ld4(p + D1)           * w1[5]
                  + ld4(p + D1 * WP - D1) * w1[6] + ld4(p + D1 * WP) * w1[7] + ld4(p + D1 * WP + D1) * w1[8];
            if (LAST) ydot += ctr * convW[c];
        }
    }

    // Finalize h_I into LDS, zero-masked outside the image (conv zero-pad).
    const float b0 = bias[I];
#pragma unroll
    for (int kk = 0; kk < NS; ++kk) {
        int s = tid + kk * 256;
        if (s < TS) {
            int row = s / SR;
            int c4 = (s - row * SR) * 4;
            int gy = gy0 - D1 + row;
            int gxb = gx0 - D1 + c4;
            bool rv = (unsigned)gy < (unsigned)IH;
#pragma unroll
            for (int j = 0; j < 4; ++j) {
                float h = acc0[kk][j] + b0;
                h = h > 0.f ? h : 0.f;
                bool v = rv && ((unsigned)(gxb + j) < (unsigned)IW);
                h_lds[row * EW + c4 + j] = v ? h : 0.f;
            }
        }
    }
    __syncthreads();

    // Phase B finish: h_I self-taps from LDS, write h_I and h_{I+1} (or y).
    const float* w1h = w1p + NC * 9;  // weight of h_I input to depth I+1
    const float b1 = bias[I + 1];
    const float* hp = h_lds + (iy + D1) * EW + (ix4 + D1);
    f4 hc, h1;
#pragma unroll
    for (int j = 0; j < 4; ++j) {
        const float* q = hp + j;
        float a = w1h[0] * q[-D1 * EW - D1] + w1h[1] * q[-D1 * EW] + w1h[2] * q[-D1 * EW + D1]
                + w1h[3] * q[-D1]           + w1h[4] * q[0]        + w1h[5] * q[D1]
                + w1h[6] * q[D1 * EW - D1]  + w1h[7] * q[D1 * EW]  + w1h[8] * q[D1 * EW + D1];
        hc[j] = q[0];
        float v = acc1[j] + a + b1;
        h1[j] = v > 0.f ? v : 0.f;
    }
    if (!LAST) {
        *(f4*)(P + (size_t)(NC * NB + b) * PLANE + offB) = hc;        // plane I+1
        *(f4*)(P + (size_t)((NC + 1) * NB + b) * PLANE + offB) = h1;  // plane I+2
    } else {
        f4 y = ydot + hc * convW[MSD_DEPTH - 1] + h1 * convW[MSD_DEPTH] + convB[0];
        y = y * soutw[0] + soutb[0];
        *(f4*)(out + ((size_t)b * IH + gy0 + iy) * IW + gx0 + ix4) = y;
    }
}

// ---------------------------------------------------------------------------
extern "C" void kernel_launch(void* const* d_in, const int* in_sizes, int n_in,
                              void* d_out, int out_size, void* d_ws, size_t ws_size,
                              hipStream_t stream) {
    const float* x     = (const float*)d_in[0];
    const float* Wmsd  = (const float*)d_in[1];
    const float* bias  = (const float*)d_in[2];
    const float* convW = (const float*)d_in[3];
    const float* convB = (const float*)d_in[4];
    const float* sinw  = (const float*)d_in[5];
    const float* sinb  = (const float*)d_in[6];
    const float* soutw = (const float*)d_in[7];
    const float* soutb = (const float*)d_in[8];
    float* out = (float*)d_out;
    float* ws  = (float*)d_ws;

    const long halo_total = (long)(WP * HP - IW * IH) * NPLANES * NB;
    int zb = (int)((halo_total + 255) / 256);
    zero_halo_kernel<<<zb, 256, 0, stream>>>(ws);

    scale_in_kernel<<<NPIX / 1024, 256, 0, stream>>>(x, ws, sinw, sinb);

#define LNCH(I) pair_kernel<I><<<1024, 256, 0, stream>>>(ws, Wmsd, bias, convW, convB, soutw, soutb, out);
    LNCH(0)  LNCH(2)  LNCH(4)  LNCH(6)  LNCH(8)
    LNCH(10) LNCH(12) LNCH(14) LNCH(16) LNCH(18)
    LNCH(20) LNCH(22) LNCH(24) LNCH(26) LNCH(28)
#undef LNCH
}

// Round 5
// 613.277 us; speedup vs baseline: 1.8204x; 1.8204x over previous
//
#include <hip/hip_runtime.h>

// MSDNet on gfx950 — round 5: unfused depth kernels, fp16 planes, wide tiles.
// Model (validated R1/R4): cost ≈ tap-wave-instructions × cache-lines-touched
// at ~1 line/cyc/CU. So: no pair fusion (no recompute), fp16 planes (half the
// lines), 256-wide rows (best lines-per-instruction), 8px/thread half8 taps.
// ws: 30 zero-halo-padded fp16 planes (x,h0..h28) x 4 batches, HALO=16 so
// interior strips are 16B-aligned. Accumulation fp32, weights fp32.
// Depth 29 fuses the 1x1 conv + output affine (h29 never materialized).

#define MSD_DEPTH 30
#define NB 4
#define IH 512
#define IW 512
#define HALO 16
#define WP (IW + 2 * HALO) /* 544 */
#define HP (IH + 2 * HALO) /* 544 */
#define PLANE ((size_t)WP * (size_t)HP) /* 295936 */
#define CSTRIDE ((size_t)NB * PLANE)
#define NPIX (NB * IH * IW) /* 1048576 */
#define NPLANES 30          /* planes 0..29 = x, h0..h28 */
#define GUARD ((size_t)(64 * WP))

typedef _Float16 h8 __attribute__((ext_vector_type(8)));   // 16B
typedef h8 h8u __attribute__((aligned(2)));
typedef float f4 __attribute__((ext_vector_type(4)));

__device__ __forceinline__ h8 ld8(const _Float16* p) { return *(const h8u*)p; }

// ---------------------------------------------------------------------------
// Zero the halo ring of all 120 subplanes (interiors are always overwritten).
__global__ __launch_bounds__(256) void zero_halo_kernel(_Float16* __restrict__ ws) {
    const int per = WP * HP - IW * IH; // 33792
    long idx = (long)blockIdx.x * 256 + threadIdx.x;
    const long total = (long)per * NPLANES * NB;
    if (idx >= total) return;
    int sub = (int)(idx / per);
    int rem = (int)(idx % per);
    int r, c;
    if (rem < HALO * WP) {                       // top rows
        r = rem / WP; c = rem % WP;
    } else if (rem < 2 * HALO * WP) {            // bottom rows
        int t = rem - HALO * WP;
        r = (IH + HALO) + t / WP; c = t % WP;
    } else {                                     // side columns
        int t = rem - 2 * HALO * WP;
        r = HALO + t / (2 * HALO);
        int u = t % (2 * HALO);
        c = (u < HALO) ? u : (IW + u);
    }
    ws[GUARD + (size_t)sub * PLANE + (size_t)r * WP + c] = (_Float16)0.f;
}

// ---------------------------------------------------------------------------
// Plane 0 = fp16(x * sin_w + sin_b).
__global__ __launch_bounds__(256) void scale_in_kernel(const float* __restrict__ x,
                                                       _Float16* __restrict__ ws,
                                                       const float* __restrict__ sw,
                                                       const float* __restrict__ sb) {
    int s = blockIdx.x * 256 + threadIdx.x; // strip of 8 px
    int idx = s * 8;
    int w = idx & (IW - 1);
    int t = idx >> 9;
    int h = t & (IH - 1);
    int b = t >> 9;
    const float sws = sw[0], sbs = sb[0];
    h8 v;
#pragma unroll
    for (int j = 0; j < 8; ++j) v[j] = (_Float16)(x[idx + j] * sws + sbs);
    *(h8*)(ws + GUARD + (size_t)b * PLANE + (size_t)(h + HALO) * WP + (w + HALO)) = v;
}

// ---------------------------------------------------------------------------
// Depth kernel I: h_I = relu(bias[I] + sum_c conv3x3_dilD(plane_c)).
// Tile 256x8, 256 threads, 8px/thread; 9 half8 tap loads per plane.
template <int I>
__global__ __launch_bounds__(256) void depth_kernel(_Float16* __restrict__ ws,
                                                    const float* __restrict__ Wmsd,
                                                    const float* __restrict__ bias,
                                                    const float* __restrict__ convW,
                                                    const float* __restrict__ convB,
                                                    const float* __restrict__ soutw,
                                                    const float* __restrict__ soutb,
                                                    float* __restrict__ out) {
    constexpr int D = (I % 10) + 1;
    constexpr int NC = I + 1;
    constexpr bool LAST = (I == MSD_DEPTH - 1);

    const int tid = threadIdx.x;
    const int bid = blockIdx.x; // 512 blocks
    // XCD band swizzle (validated R4: keeps planes LLC/L2-resident):
    // xcd = bid&7; 2 XCDs per image; each owns a contiguous 256-row band.
    const int xcd = bid & 7;
    const int k = bid >> 3;                  // 0..63
    const int b = xcd >> 1;                  // image
    const int ty = (xcd & 1) * 32 + (k >> 1);// 0..63 (8-px tile rows)
    const int tx = k & 1;                    // 0..1  (256-px tile cols)
    const int gx0 = tx * 256, gy0 = ty * 8;

    const int sx = (tid & 31) * 8;           // 32 strips per 256-px row
    const int sy = tid >> 5;                 // 8 rows
    const size_t ioff = (size_t)(gy0 + sy + HALO) * WP + (gx0 + sx + HALO);

    const _Float16* const P = ws + GUARD;
    const _Float16* pbase = P + (size_t)b * PLANE + ioff;

    float acc[8];
    float ydot[8];
#pragma unroll
    for (int j = 0; j < 8; ++j) { acc[j] = 0.f; ydot[j] = 0.f; }

    const float* wr = Wmsd + (size_t)I * (MSD_DEPTH * 9);
    for (int c = 0; c < NC; ++c) {
        const _Float16* p = pbase + (size_t)c * CSTRIDE;
        h8 t00 = ld8(p - D * WP - D), t01 = ld8(p - D * WP), t02 = ld8(p - D * WP + D);
        h8 t10 = ld8(p - D),          t11 = ld8(p),          t12 = ld8(p + D);
        h8 t20 = ld8(p + D * WP - D), t21 = ld8(p + D * WP), t22 = ld8(p + D * WP + D);
        const float* wk = wr + c * 9;
        const float w0 = wk[0], w1 = wk[1], w2 = wk[2], w3 = wk[3], w4 = wk[4],
                    w5 = wk[5], w6 = wk[6], w7 = wk[7], w8 = wk[8];
        const float cw = LAST ? convW[c] : 0.f;
#pragma unroll
        for (int j = 0; j < 8; ++j) {
            float s = acc[j];
            s += w0 * (float)t00[j]; s += w1 * (float)t01[j]; s += w2 * (float)t02[j];
            s += w3 * (float)t10[j]; s += w4 * (float)t11[j]; s += w5 * (float)t12[j];
            s += w6 * (float)t20[j]; s += w7 * (float)t21[j]; s += w8 * (float)t22[j];
            acc[j] = s;
            if (LAST) ydot[j] += cw * (float)t11[j];
        }
    }

    const float b0 = bias[I];
    if (!LAST) {
        _Float16* q = ws + GUARD + (size_t)(NC * NB + b) * PLANE + ioff;
        h8 hv;
#pragma unroll
        for (int j = 0; j < 8; ++j) {
            float h = acc[j] + b0;
            hv[j] = (_Float16)(h > 0.f ? h : 0.f);
        }
        *(h8*)q = hv;
    } else {
        const float cw29 = convW[MSD_DEPTH];
        const float cb = convB[0], ow = soutw[0], ob = soutb[0];
        float* q = out + ((size_t)(b * IH) + gy0 + sy) * IW + gx0 + sx;
        f4 y0, y1;
#pragma unroll
        for (int j = 0; j < 8; ++j) {
            float h = acc[j] + b0;
            h = h > 0.f ? h : 0.f;
            float y = ydot[j] + cw29 * h + cb;
            y = y * ow + ob;
            if (j < 4) y0[j] = y; else y1[j - 4] = y;
        }
        *(f4*)q = y0;
        *(f4*)(q + 4) = y1;
    }
}

// ---------------------------------------------------------------------------
extern "C" void kernel_launch(void* const* d_in, const int* in_sizes, int n_in,
                              void* d_out, int out_size, void* d_ws, size_t ws_size,
                              hipStream_t stream) {
    const float* x     = (const float*)d_in[0];
    const float* Wmsd  = (const float*)d_in[1];
    const float* bias  = (const float*)d_in[2];
    const float* convW = (const float*)d_in[3];
    const float* convB = (const float*)d_in[4];
    const float* sinw  = (const float*)d_in[5];
    const float* sinb  = (const float*)d_in[6];
    const float* soutw = (const float*)d_in[7];
    const float* soutb = (const float*)d_in[8];
    float* out = (float*)d_out;
    _Float16* ws = (_Float16*)d_ws;

    const long halo_total = (long)(WP * HP - IW * IH) * NPLANES * NB;
    int zb = (int)((halo_total + 255) / 256);
    zero_halo_kernel<<<zb, 256, 0, stream>>>(ws);

    scale_in_kernel<<<NPIX / 8 / 256, 256, 0, stream>>>(x, ws, sinw, sinb);

#define LNCH(I) depth_kernel<I><<<512, 256, 0, stream>>>(ws, Wmsd, bias, convW, convB, soutw, soutb, out);
    LNCH(0)  LNCH(1)  LNCH(2)  LNCH(3)  LNCH(4)
    LNCH(5)  LNCH(6)  LNCH(7)  LNCH(8)  LNCH(9)
    LNCH(10) LNCH(11) LNCH(12) LNCH(13) LNCH(14)
    LNCH(15) LNCH(16) LNCH(17) LNCH(18) LNCH(19)
    LNCH(20) LNCH(21) LNCH(22) LNCH(23) LNCH(24)
    LNCH(25) LNCH(26) LNCH(27) LNCH(28) LNCH(29)
#undef LNCH
}